// Round 8
// baseline (116.263 us; speedup 1.0000x reference)
//
#include <hip/hip_runtime.h>
#include <hip/hip_bf16.h>

// ILA layer (all fp32): key = W@ft, query = W@fk (1x1 conv, shared W),
// sim[p,k] = <query[p], key[neighbor_k(p)]> over 9x9 window (zero-padded keys),
// weight = softmax_k(sim)  (OOB entries participate with sim=0),
// out[c,p] = sum_k weight[k] * ft[c, neighbor_k(p)]  (zero-padded ft).
// n=2, c=128, h=w=64, L=9 (81 neighbors).

#define Hh 64
#define Ww 64
#define Cc 128
#define Nn 2
#define KK 81
#define HW (Hh * Ww)          // 4096
#define CHW (Cc * HW)         // 524288
#define P_TOT (Nn * HW)       // 8192

__device__ __forceinline__ void fma4(float4& a, const float4 b, const float s) {
    a.x += b.x * s; a.y += b.y * s; a.z += b.z * s; a.w += b.w * s;
}

// ---------------- Kernel A: projection (K = W*ft, Q = W*fk), pixel-major fp32 out.
// 256 blocks x 128 thr; 32 px/block; thread tile = 4 px x 8 out x {K,Q}.
// Per ii: 4 LDS reads feed 64 FMAs (1 B/MAC); acc quads are out-contiguous -> direct f4 store.
// LDS 53.7 KB -> 2 blocks/CU co-resident (all 256 blocks resident device-wide).
__global__ __launch_bounds__(128) void proj_kernel(const float* __restrict__ ft,
                                                   const float* __restrict__ fk,
                                                   const float* __restrict__ Wm,
                                                   float* __restrict__ Qbuf,
                                                   float* __restrict__ Kbuf) {
    __shared__ __align__(16) float Wl[32 * 132];   // [ii][o] chunk of W^T
    __shared__ __align__(16) float xkl[128 * 36];  // [i][pl]
    __shared__ __align__(16) float xql[128 * 36];
    const int t = threadIdx.x;
    const int p0 = blockIdx.x * 32;       // 4096 % 32 == 0: never crosses n
    const int nn = p0 >> 12;
    const int gbase = nn * CHW + (p0 & 4095);

#pragma unroll 4
    for (int e = t; e < 128 * 32; e += 128) {       // stage x tiles (coalesced 128B runs)
        const int c = e >> 5, pl = e & 31;
        xkl[c * 36 + pl] = ft[gbase + c * HW + pl];
        xql[c * 36 + pl] = fk[gbase + c * HW + pl];
    }

    const int po = t & 7;                 // 8 pixel groups x 4 px
    const int oo = t >> 3;                // 16 out groups x 8 out
    float4 aK[4][2], aQ[4][2];
#pragma unroll
    for (int i = 0; i < 4; ++i) {
        aK[i][0] = make_float4(0,0,0,0); aK[i][1] = aK[i][0];
        aQ[i][0] = aK[i][0];             aQ[i][1] = aK[i][0];
    }

    for (int ch = 0; ch < 4; ++ch) {
#pragma unroll 4
        for (int e = t; e < 128 * 32; e += 128) {   // Wl[ii][o] <- Wm[o][ch*32+ii]
            const int o = e >> 5, ii = e & 31;
            Wl[ii * 132 + o] = Wm[o * 128 + (ch << 5) + ii];
        }
        __syncthreads();
#pragma unroll 4
        for (int ii = 0; ii < 32; ++ii) {
            const int i = (ch << 5) + ii;
            const float4 wA = *(const float4*)&Wl[ii * 132 + (oo << 3)];
            const float4 wB = *(const float4*)&Wl[ii * 132 + (oo << 3) + 4];
            const float4 k4 = *(const float4*)&xkl[i * 36 + (po << 2)];
            const float4 q4 = *(const float4*)&xql[i * 36 + (po << 2)];
            fma4(aK[0][0], wA, k4.x); fma4(aK[0][1], wB, k4.x);
            fma4(aK[1][0], wA, k4.y); fma4(aK[1][1], wB, k4.y);
            fma4(aK[2][0], wA, k4.z); fma4(aK[2][1], wB, k4.z);
            fma4(aK[3][0], wA, k4.w); fma4(aK[3][1], wB, k4.w);
            fma4(aQ[0][0], wA, q4.x); fma4(aQ[0][1], wB, q4.x);
            fma4(aQ[1][0], wA, q4.y); fma4(aQ[1][1], wB, q4.y);
            fma4(aQ[2][0], wA, q4.z); fma4(aQ[2][1], wB, q4.z);
            fma4(aQ[3][0], wA, q4.w); fma4(aQ[3][1], wB, q4.w);
        }
        __syncthreads();
    }

#pragma unroll
    for (int pp = 0; pp < 4; ++pp) {      // acc quads are out-contiguous: no transpose
        const size_t base = (size_t)(p0 + (po << 2) + pp) * 128 + (oo << 3);
        *(float4*)&Kbuf[base]     = aK[pp][0];
        *(float4*)&Kbuf[base + 4] = aK[pp][1];
        *(float4*)&Qbuf[base]     = aQ[pp][0];
        *(float4*)&Qbuf[base + 4] = aQ[pp][1];
    }
}

// ---------------- Kernel B (fused): sim + softmax + weighting. Block = 8-px row strip.
// LDS caps occupancy at 2 blocks/CU (8 waves), so VGPR<=256 is free: dot loop
// unrolled 8 (32 b128 in flight) to stream LDS latency instead of stalling on it.
__global__ __launch_bounds__(256, 2) void sim_weight_kernel(const float* __restrict__ Qbuf,
                                                            const float* __restrict__ Kbuf,
                                                            const float* __restrict__ ft,
                                                            float* __restrict__ out) {
    __shared__ __align__(16) float lds[20168];
    float* Ksw  = lds;            // 18432 floats (dead after dots)
    float* Qsw  = lds + 18432;    // 1024   (dead after dots)
    float* ftl  = lds;            // 19008 = 144 rows * 132 (aliases Ksw+Qsw after B2)
    float* redM = lds + 19456;    // 32
    float* redS = lds + 19488;    // 32
    float* simb = lds + 19520;    // 648

    const int t  = threadIdx.x;
    const int b  = blockIdx.x;
    const int x0 = (b & 7) << 3;
    const int y  = (b >> 3) & 63;
    const int nn = b >> 9;
    const int pg0 = (nn << 12) + (y << 6) + x0;

    // ---- stage K: zero-padded 9x16 window, XOR-swizzled float4 chunks
#pragma unroll 4
    for (int e = t; e < 144 * 32; e += 256) {
        const int v = e >> 5, ci = e & 31;
        const int gx = x0 + (v & 15) - 4;
        const int gy = y + (v >> 4) - 4;
        float4 val = make_float4(0, 0, 0, 0);
        if ((unsigned)gx < 64u && (unsigned)gy < 64u)
            val = *(const float4*)&Kbuf[(size_t)((nn << 12) + (gy << 6) + gx) * 128 + (ci << 2)];
        *(float4*)&Ksw[(v << 7) + (((ci ^ (v & 31)) << 2))] = val;
    }
    {   // stage Q: 8 vectors, 256 threads = exactly 8*32 chunks
        const int v = t >> 5, ci = t & 31;
        const float4 val = *(const float4*)&Qbuf[(size_t)(pg0 + v) * 128 + (ci << 2)];
        *(float4*)&Qsw[(v << 7) + ((ci ^ v) << 2)] = val;
    }
    __syncthreads();   // B1

    // ---- dots: thread -> (pixel p, k in {kb, kb+32, kb+64})
    const int p = t & 7, kb = t >> 3;
    const bool has2 = (kb + 64 < KK);
    const int k0 = kb, k1 = kb + 32, k2 = has2 ? kb + 64 : kb;
    const int v0 = (k0 / 9) * 16 + p + k0 % 9;
    const int v1 = (k1 / 9) * 16 + p + k1 % 9;
    const int v2 = (k2 / 9) * 16 + p + k2 % 9;
    const int b0 = v0 << 7, m0 = v0 & 31;
    const int b1 = v1 << 7, m1 = v1 & 31;
    const int b2 = v2 << 7, m2 = v2 & 31;
    const int bq = p << 7;
    float4 a0 = make_float4(0,0,0,0), a1 = a0, a2 = a0;
#pragma unroll 8
    for (int ci = 0; ci < 32; ++ci) {
        const float4 q4 = *(const float4*)&Qsw[bq + ((ci ^ p) << 2)];
        const float4 kA = *(const float4*)&Ksw[b0 + ((ci ^ m0) << 2)];
        const float4 kB = *(const float4*)&Ksw[b1 + ((ci ^ m1) << 2)];
        const float4 kC = *(const float4*)&Ksw[b2 + ((ci ^ m2) << 2)];
        a0.x += q4.x*kA.x; a0.y += q4.y*kA.y; a0.z += q4.z*kA.z; a0.w += q4.w*kA.w;
        a1.x += q4.x*kB.x; a1.y += q4.y*kB.y; a1.z += q4.z*kB.z; a1.w += q4.w*kB.w;
        a2.x += q4.x*kC.x; a2.y += q4.y*kC.y; a2.z += q4.z*kC.z; a2.w += q4.w*kC.w;
    }
    const float s0 = a0.x + a0.y + a0.z + a0.w;
    const float s1 = a1.x + a1.y + a1.z + a1.w;
    const float s2 = a2.x + a2.y + a2.z + a2.w;
    __syncthreads();   // B2: Ksw/Qsw dead, safe to overwrite

    // ---- restage ft into ftl[row*132 + c], row = r*16+xx (stride 132: staging
    // writes 2-way (free), weighting b128 reads at the structural bank floor)
#pragma unroll 4
    for (int e = t; e < 4608; e += 256) {           // 9 r x 128 c x 4 j
        const int j = e & 3, c = (e >> 2) & 127, r = e >> 9;
        const int gx0 = x0 - 4 + (j << 2);          // quad fully in or fully out
        const int gy = y + r - 4;
        float4 v = make_float4(0, 0, 0, 0);
        if ((unsigned)gy < 64u && (unsigned)gx0 < 64u)
            v = *(const float4*)&ft[(size_t)((nn * Cc + c) << 12) + (gy << 6) + gx0];
        const int base = ((r << 4) + (j << 2)) * 132 + c;
        ftl[base] = v.x; ftl[base + 132] = v.y; ftl[base + 264] = v.z; ftl[base + 396] = v.w;
    }

    // ---- softmax in registers: reduce over lanes sharing p (bits 3..5 of lane id)
    float m = fmaxf(s0, s1);
    if (has2) m = fmaxf(m, s2);
#pragma unroll
    for (int off = 8; off <= 32; off <<= 1) m = fmaxf(m, __shfl_xor(m, off));
    if ((t & 56) == 0) redM[((t >> 6) << 3) + p] = m;   // one lane per (wave, p)
    __syncthreads();   // B3 (also covers ftl writes)
    float mm = fmaxf(fmaxf(redM[p], redM[8 + p]), fmaxf(redM[16 + p], redM[24 + p]));
    const float e0 = __expf(s0 - mm);
    const float e1 = __expf(s1 - mm);
    const float e2 = has2 ? __expf(s2 - mm) : 0.f;
    simb[k0 * 8 + p] = e0;
    simb[k1 * 8 + p] = e1;
    if (has2) simb[(kb + 64) * 8 + p] = e2;
    float s = e0 + e1 + e2;
#pragma unroll
    for (int off = 8; off <= 32; off <<= 1) s += __shfl_xor(s, off);
    if ((t & 56) == 0) redS[((t >> 6) << 3) + p] = s;
    __syncthreads();   // B4
    const float inv = 1.f / (redS[p] + redS[8 + p] + redS[16 + p] + redS[24 + p]);

    // ---- weighting: thread = (p, cq); 4 channels per thread.
    // r rolled, dx fully unrolled (9 f4 + 9 w live: no spill risk)
    const int cq = t >> 3;
    float4 acc = make_float4(0, 0, 0, 0);
    for (int r = 0; r < 9; ++r) {
        const int rb = ((r << 4) + p) * 132 + (cq << 2);
        const int k9 = r * 9;
#pragma unroll
        for (int dx = 0; dx < 9; ++dx) {
            const float w = simb[(k9 + dx) * 8 + p];    // 8-lane broadcast
            const float4 f4 = *(const float4*)&ftl[rb + dx * 132];
            fma4(acc, f4, w);
        }
    }
    const size_t ob = (size_t)((nn * Cc + (cq << 2)) << 12) + (y << 6) + x0 + p;
    out[ob]          = acc.x * inv;
    out[ob + HW]     = acc.y * inv;
    out[ob + 2*HW]   = acc.z * inv;
    out[ob + 3*HW]   = acc.w * inv;
}

extern "C" void kernel_launch(void* const* d_in, const int* in_sizes, int n_in,
                              void* d_out, int out_size, void* d_ws, size_t ws_size,
                              hipStream_t stream) {
    const float* ft = (const float*)d_in[0];
    const float* fk = (const float*)d_in[1];
    const float* Wm = (const float*)d_in[2];
    float* out = (float*)d_out;

    float* ws   = (float*)d_ws;          // 8 MB: Q(4MB) + K(4MB)
    float* Qbuf = ws;                    // [p][c]  8192*128
    float* Kbuf = ws + 1048576;          // [p][c]  8192*128

    proj_kernel<<<256, 128, 0, stream>>>(ft, fk, Wm, Qbuf, Kbuf);
    sim_weight_kernel<<<1024, 256, 0, stream>>>(Qbuf, Kbuf, ft, out);
}

// Round 9
// 98.544 us; speedup vs baseline: 1.1798x; 1.1798x over previous
//
#include <hip/hip_runtime.h>
#include <hip/hip_bf16.h>

// ILA layer (all fp32 I/O): key = W@ft, query = W@fk (1x1 conv, shared W),
// sim[p,k] = <query[p], key[neighbor_k(p)]> over 9x9 window (zero-padded keys),
// weight = softmax_k(sim)  (OOB entries participate with sim=0),
// out[c,p] = sum_k weight[k] * ft[c, neighbor_k(p)]  (zero-padded ft).
// n=2, c=128, h=w=64, L=9 (81 neighbors).

#define Hh 64
#define Ww 64
#define Cc 128
#define Nn 2
#define KK 81
#define HW (Hh * Ww)          // 4096
#define CHW (Cc * HW)         // 524288
#define P_TOT (Nn * HW)       // 8192

typedef _Float16 h8 __attribute__((ext_vector_type(8)));
typedef _Float16 h4 __attribute__((ext_vector_type(4)));
typedef _Float16 h2 __attribute__((ext_vector_type(2)));

__device__ __forceinline__ void fma4(float4& a, const float4 b, const float s) {
    a.x += b.x * s; a.y += b.y * s; a.z += b.z * s; a.w += b.w * s;
}

__device__ __forceinline__ float dot8(const h8 a, const h8 b, float acc) {
#if __has_builtin(__builtin_amdgcn_fdot2)
    h2 a0 = {a[0], a[1]}, b0 = {b[0], b[1]};
    h2 a1 = {a[2], a[3]}, b1 = {b[2], b[3]};
    h2 a2 = {a[4], a[5]}, b2 = {b[4], b[5]};
    h2 a3 = {a[6], a[7]}, b3 = {b[6], b[7]};
    acc = __builtin_amdgcn_fdot2(a0, b0, acc, false);
    acc = __builtin_amdgcn_fdot2(a1, b1, acc, false);
    acc = __builtin_amdgcn_fdot2(a2, b2, acc, false);
    acc = __builtin_amdgcn_fdot2(a3, b3, acc, false);
#else
#pragma unroll
    for (int i = 0; i < 8; ++i) acc += (float)a[i] * (float)b[i];
#endif
    return acc;
}

__device__ __forceinline__ h8 cvt_h8(const float4 A, const float4 B) {
    h8 h;
    h[0] = (_Float16)A.x; h[1] = (_Float16)A.y; h[2] = (_Float16)A.z; h[3] = (_Float16)A.w;
    h[4] = (_Float16)B.x; h[5] = (_Float16)B.y; h[6] = (_Float16)B.z; h[7] = (_Float16)B.w;
    return h;
}

// ---------------- Kernel A: projection (K = W*ft, Q = W*fk) — round-7 measured version.
// 256 blocks x 256 thr; 32 px/block; thread tile = 4 px x 4 out x {K,Q}; unroll caps 4.
__global__ __launch_bounds__(256) void proj_kernel(const float* __restrict__ ft,
                                                   const float* __restrict__ fk,
                                                   const float* __restrict__ Wm,
                                                   float* __restrict__ Qbuf,
                                                   float* __restrict__ Kbuf) {
    __shared__ __align__(16) float Wl[32 * 132];   // [ii][o] chunk of W^T
    __shared__ __align__(16) float xkl[128 * 36];  // [i][pl]
    __shared__ __align__(16) float xql[128 * 36];
    const int t = threadIdx.x;
    const int p0 = blockIdx.x * 32;       // 4096 % 32 == 0: never crosses n
    const int nn = p0 >> 12;
    const int gbase = nn * CHW + (p0 & 4095);

    for (int e = t; e < 128 * 32; e += 256) {       // stage x tiles (coalesced 128B runs)
        const int c = e >> 5, pl = e & 31;
        xkl[c * 36 + pl] = ft[gbase + c * HW + pl];
        xql[c * 36 + pl] = fk[gbase + c * HW + pl];
    }

    const int po = t & 7;                 // 8 pixel groups x 4 px
    const int oo = t >> 3;                // 32 out groups x 4 out
    float4 accK[4], accQ[4];
#pragma unroll
    for (int i = 0; i < 4; ++i) { accK[i] = make_float4(0,0,0,0); accQ[i] = make_float4(0,0,0,0); }

    for (int ch = 0; ch < 4; ++ch) {
        for (int e = t; e < 128 * 32; e += 256) {   // Wl[ii][o] <- Wm[o][ch*32+ii]
            const int o = e >> 5, ii = e & 31;
            Wl[ii * 132 + o] = Wm[o * 128 + (ch << 5) + ii];
        }
        __syncthreads();
#pragma unroll 4
        for (int ii = 0; ii < 32; ++ii) {
            const int i = (ch << 5) + ii;
            const float4 w4 = *(const float4*)&Wl[ii * 132 + (oo << 2)];
            const float4 k4 = *(const float4*)&xkl[i * 36 + (po << 2)];
            const float4 q4 = *(const float4*)&xql[i * 36 + (po << 2)];
            fma4(accK[0], k4, w4.x); fma4(accK[1], k4, w4.y);
            fma4(accK[2], k4, w4.z); fma4(accK[3], k4, w4.w);
            fma4(accQ[0], q4, w4.x); fma4(accQ[1], q4, w4.y);
            fma4(accQ[2], q4, w4.z); fma4(accQ[3], q4, w4.w);
        }
        __syncthreads();
    }

    const int pbase = p0 + (po << 2);
    const float4 vK0 = make_float4(accK[0].x, accK[1].x, accK[2].x, accK[3].x);
    const float4 vK1 = make_float4(accK[0].y, accK[1].y, accK[2].y, accK[3].y);
    const float4 vK2 = make_float4(accK[0].z, accK[1].z, accK[2].z, accK[3].z);
    const float4 vK3 = make_float4(accK[0].w, accK[1].w, accK[2].w, accK[3].w);
    const float4 vQ0 = make_float4(accQ[0].x, accQ[1].x, accQ[2].x, accQ[3].x);
    const float4 vQ1 = make_float4(accQ[0].y, accQ[1].y, accQ[2].y, accQ[3].y);
    const float4 vQ2 = make_float4(accQ[0].z, accQ[1].z, accQ[2].z, accQ[3].z);
    const float4 vQ3 = make_float4(accQ[0].w, accQ[1].w, accQ[2].w, accQ[3].w);
    *(float4*)&Kbuf[(size_t)(pbase    ) * 128 + (oo << 2)] = vK0;
    *(float4*)&Kbuf[(size_t)(pbase + 1) * 128 + (oo << 2)] = vK1;
    *(float4*)&Kbuf[(size_t)(pbase + 2) * 128 + (oo << 2)] = vK2;
    *(float4*)&Kbuf[(size_t)(pbase + 3) * 128 + (oo << 2)] = vK3;
    *(float4*)&Qbuf[(size_t)(pbase    ) * 128 + (oo << 2)] = vQ0;
    *(float4*)&Qbuf[(size_t)(pbase + 1) * 128 + (oo << 2)] = vQ1;
    *(float4*)&Qbuf[(size_t)(pbase + 2) * 128 + (oo << 2)] = vQ2;
    *(float4*)&Qbuf[(size_t)(pbase + 3) * 128 + (oo << 2)] = vQ3;
}

// ---------------- Kernel B (fused): sim + softmax + weighting. Block = 8-px row strip.
// K/Q/ft staged in LDS as fp16 (fp32 accumulate via v_dot2_f32_f16):
// LDS 79 KB -> ~40 KB => 4 blocks/CU (16 waves/CU) and half the dot-phase LDS bytes.
__global__ __launch_bounds__(256, 4) void sim_weight_kernel(const float* __restrict__ Qbuf,
                                                            const float* __restrict__ Kbuf,
                                                            const float* __restrict__ ft,
                                                            float* __restrict__ out) {
    __shared__ __align__(16) unsigned char smem[40464];
    _Float16* Ksw  = (_Float16*)smem;             // 18432 halves [0, 36864)
    _Float16* Qsw  = (_Float16*)(smem + 36864);   // 1024 halves  [36864, 38912)
    _Float16* ftl  = (_Float16*)smem;             // 19008 halves [0, 38016) — aliases Ksw/Qsw after B2
    _Float16* simb = (_Float16*)(smem + 38912);   // 648 halves   [38912, 40208)
    float*    redM = (float*)(smem + 40208);      // 32 floats    [40208, 40336)
    float*    redS = (float*)(smem + 40336);      // 32 floats    [40336, 40464)

    const int t  = threadIdx.x;
    const int b  = blockIdx.x;
    const int x0 = (b & 7) << 3;
    const int y  = (b >> 3) & 63;
    const int nn = b >> 9;
    const int pg0 = (nn << 12) + (y << 6) + x0;

    // ---- stage K: zero-padded 9x16 window, fp16, XOR-swizzled 16B chunks (8 ch each)
#pragma unroll 3
    for (int e = t; e < 144 * 16; e += 256) {     // 2304 chunks, 9 iters
        const int v = e >> 4, ci = e & 15;
        const int gx = x0 + (v & 15) - 4;
        const int gy = y + (v >> 4) - 4;
        float4 A = make_float4(0,0,0,0), B = A;
        if ((unsigned)gx < 64u && (unsigned)gy < 64u) {
            const float* kp = &Kbuf[(size_t)((nn << 12) + (gy << 6) + gx) * 128 + (ci << 3)];
            A = *(const float4*)kp;
            B = *(const float4*)(kp + 4);
        }
        *(h8*)&Ksw[(v << 7) + ((ci ^ (v & 15)) << 3)] = cvt_h8(A, B);
    }
    if (t < 128) {   // stage Q: 8 vectors x 16 chunks
        const int v = t >> 4, ci = t & 15;
        const float* qp = &Qbuf[(size_t)(pg0 + v) * 128 + (ci << 3)];
        const float4 A = *(const float4*)qp;
        const float4 B = *(const float4*)(qp + 4);
        *(h8*)&Qsw[(v << 7) + ((ci ^ v) << 3)] = cvt_h8(A, B);
    }
    __syncthreads();   // B1

    // ---- dots: thread -> (pixel p, k in {kb, kb+32, kb+64}), fp16 inputs, fp32 accum
    const int p = t & 7, kb = t >> 3;
    const bool has2 = (kb + 64 < KK);
    const int k0 = kb, k1 = kb + 32, k2 = has2 ? kb + 64 : kb;
    const int v0 = (k0 / 9) * 16 + p + k0 % 9;
    const int v1 = (k1 / 9) * 16 + p + k1 % 9;
    const int v2 = (k2 / 9) * 16 + p + k2 % 9;
    const int b0 = v0 << 7, m0 = v0 & 15;
    const int b1 = v1 << 7, m1 = v1 & 15;
    const int b2 = v2 << 7, m2 = v2 & 15;
    const int bq = p << 7;
    float s0 = 0.f, s1 = 0.f, s2 = 0.f;
#pragma unroll 4
    for (int ci = 0; ci < 16; ++ci) {
        const h8 q8 = *(const h8*)&Qsw[bq + ((ci ^ p) << 3)];
        const h8 kA = *(const h8*)&Ksw[b0 + ((ci ^ m0) << 3)];
        const h8 kB = *(const h8*)&Ksw[b1 + ((ci ^ m1) << 3)];
        const h8 kC = *(const h8*)&Ksw[b2 + ((ci ^ m2) << 3)];
        s0 = dot8(q8, kA, s0);
        s1 = dot8(q8, kB, s1);
        s2 = dot8(q8, kC, s2);
    }
    __syncthreads();   // B2: Ksw/Qsw dead, safe to overwrite with ftl

    // ---- restage ft (fp16) into ftl[row*132 + c], row = r*16+xx
#pragma unroll 2
    for (int e = t; e < 4608; e += 256) {           // 9 r x 128 c x 4 j
        const int j = e & 3, c = (e >> 2) & 127, r = e >> 9;
        const int gx0 = x0 - 4 + (j << 2);          // quad fully in or fully out
        const int gy = y + r - 4;
        float4 v = make_float4(0, 0, 0, 0);
        if ((unsigned)gy < 64u && (unsigned)gx0 < 64u)
            v = *(const float4*)&ft[(size_t)((nn * Cc + c) << 12) + (gy << 6) + gx0];
        const int base = ((r << 4) + (j << 2)) * 132 + c;
        ftl[base]       = (_Float16)v.x;
        ftl[base + 132] = (_Float16)v.y;
        ftl[base + 264] = (_Float16)v.z;
        ftl[base + 396] = (_Float16)v.w;
    }

    // ---- softmax in registers: reduce over lanes sharing p (bits 3..5 of lane id)
    float m = fmaxf(s0, s1);
    if (has2) m = fmaxf(m, s2);
#pragma unroll
    for (int off = 8; off <= 32; off <<= 1) m = fmaxf(m, __shfl_xor(m, off));
    if ((t & 56) == 0) redM[((t >> 6) << 3) + p] = m;   // one lane per (wave, p)
    __syncthreads();   // B3 (also covers ftl writes)
    float mm = fmaxf(fmaxf(redM[p], redM[8 + p]), fmaxf(redM[16 + p], redM[24 + p]));
    const float e0 = __expf(s0 - mm);
    const float e1 = __expf(s1 - mm);
    const float e2 = has2 ? __expf(s2 - mm) : 0.f;
    simb[k0 * 8 + p] = (_Float16)e0;
    simb[k1 * 8 + p] = (_Float16)e1;
    if (has2) simb[(kb + 64) * 8 + p] = (_Float16)e2;
    float s = e0 + e1 + e2;
#pragma unroll
    for (int off = 8; off <= 32; off <<= 1) s += __shfl_xor(s, off);
    if ((t & 56) == 0) redS[((t >> 6) << 3) + p] = s;
    __syncthreads();   // B4
    const float inv = 1.f / (redS[p] + redS[8 + p] + redS[16 + p] + redS[24 + p]);

    // ---- weighting: thread = (p, cq); 4 channels per thread, fp16 ftl, fp32 accum
    const int cq = t >> 3;
    float4 acc = make_float4(0, 0, 0, 0);
    for (int r = 0; r < 9; ++r) {
        const int rb = ((r << 4) + p) * 132 + (cq << 2);
        const int k9 = r * 9;
#pragma unroll
        for (int dx = 0; dx < 9; ++dx) {
            const float w = (float)simb[(k9 + dx) * 8 + p];  // 8-lane broadcast
            const h4 f = *(const h4*)&ftl[rb + dx * 132];
            acc.x += (float)f[0] * w;
            acc.y += (float)f[1] * w;
            acc.z += (float)f[2] * w;
            acc.w += (float)f[3] * w;
        }
    }
    const size_t ob = (size_t)((nn * Cc + (cq << 2)) << 12) + (y << 6) + x0 + p;
    out[ob]          = acc.x * inv;
    out[ob + HW]     = acc.y * inv;
    out[ob + 2*HW]   = acc.z * inv;
    out[ob + 3*HW]   = acc.w * inv;
}

extern "C" void kernel_launch(void* const* d_in, const int* in_sizes, int n_in,
                              void* d_out, int out_size, void* d_ws, size_t ws_size,
                              hipStream_t stream) {
    const float* ft = (const float*)d_in[0];
    const float* fk = (const float*)d_in[1];
    const float* Wm = (const float*)d_in[2];
    float* out = (float*)d_out;

    float* ws   = (float*)d_ws;          // 8 MB: Q(4MB) + K(4MB)
    float* Qbuf = ws;                    // [p][c]  8192*128
    float* Kbuf = ws + 1048576;          // [p][c]  8192*128

    proj_kernel<<<256, 256, 0, stream>>>(ft, fk, Wm, Qbuf, Kbuf);
    sim_weight_kernel<<<1024, 256, 0, stream>>>(Qbuf, Kbuf, ft, out);
}